// Round 3
// baseline (108.846 us; speedup 1.0000x reference)
//
#include <hip/hip_runtime.h>
#include <math.h>

// keypoints [B,3,M] f32, pc [B,3,N] f32.
#define BATCH 4
#define M 1024
#define N 32768
#define NSPLIT 256                 // pc chunks per batch
#define CHUNK (N / NSPLIT)         // 128 points staged in LDS per block
#define KPT 4                      // keypoints per thread (256 thr * 4 = 1024 = M)
#define TPB 256
#define ROWS (BATCH * M)           // 4096

// ws layout (all plain float, no atomics):
//   pws[NSPLIT][ROWS]   partial min-d2 per chunk  = 4 MiB
//   bsum[32]            per-block sums from K2
#define BSUM_OFF (NSPLIT * ROWS)

__global__ __launch_bounds__(TPB) void p2p_partial(
        const float* __restrict__ kp, const float* __restrict__ pc,
        float* __restrict__ pws) {
    __shared__ __align__(16) float px[CHUNK];
    __shared__ __align__(16) float py[CHUNK];
    __shared__ __align__(16) float pz[CHUNK];
    __shared__ __align__(16) float pw[CHUNK];    // -0.5 * ||p||^2

    const int b = blockIdx.x / NSPLIT;
    const int c = blockIdx.x % NSPLIT;
    const int t = threadIdx.x;

    // Stage one pc chunk into LDS (coalesced), precompute -||p||^2/2.
    const float* pcb = pc + (size_t)b * 3 * N + c * CHUNK;
    if (t < CHUNK) {
        float x = pcb[t], y = pcb[N + t], z = pcb[2 * N + t];
        px[t] = x; py[t] = y; pz[t] = z;
        pw[t] = -0.5f * fmaf(x, x, fmaf(y, y, z * z));
    }

    // Each thread owns KPT keypoints in registers (coalesced loads).
    const float* kpb = kp + (size_t)b * 3 * M;
    float kx[KPT], ky[KPT], kz[KPT], k2[KPT], mq[KPT];
#pragma unroll
    for (int k = 0; k < KPT; ++k) {
        int m = t + k * TPB;
        kx[k] = kpb[m];
        ky[k] = kpb[M + m];
        kz[k] = kpb[2 * M + m];
        k2[k] = fmaf(kx[k], kx[k], fmaf(ky[k], ky[k], kz[k] * kz[k]));
        mq[k] = -INFINITY;
    }
    __syncthreads();

    // Hot loop: min_p ||k-p||^2 = k2 - 2*max_p(k.p - ||p||^2/2).
    // Per pair: 3 fma + shared max3. 4 ds_read_b128 + ~60 VALU per iter.
#pragma unroll 2
    for (int j = 0; j < CHUNK; j += 4) {
        float4 vx = *(const float4*)&px[j];
        float4 vy = *(const float4*)&py[j];
        float4 vz = *(const float4*)&pz[j];
        float4 vw = *(const float4*)&pw[j];
        float X[4] = {vx.x, vx.y, vx.z, vx.w};
        float Y[4] = {vy.x, vy.y, vy.z, vy.w};
        float Z[4] = {vz.x, vz.y, vz.z, vz.w};
        float W[4] = {vw.x, vw.y, vw.z, vw.w};
#pragma unroll
        for (int k = 0; k < KPT; ++k) {
            float q0 = fmaf(kz[k], Z[0], fmaf(ky[k], Y[0], fmaf(kx[k], X[0], W[0])));
            float q1 = fmaf(kz[k], Z[1], fmaf(ky[k], Y[1], fmaf(kx[k], X[1], W[1])));
            float q2 = fmaf(kz[k], Z[2], fmaf(ky[k], Y[2], fmaf(kx[k], X[2], W[2])));
            float q3 = fmaf(kz[k], Z[3], fmaf(ky[k], Y[3], fmaf(kx[k], X[3], W[3])));
            // fmaxf chains fuse to v_max3_f32 on gfx950
            mq[k] = fmaxf(fmaxf(mq[k], q0), q1);
            mq[k] = fmaxf(fmaxf(mq[k], q2), q3);
        }
    }

    // Epilogue: d2 = k2 - 2*qmax, clamp >= 0. Plain coalesced streaming store
    // (no atomics, no fence; cross-kernel visibility via end-of-kernel release).
    float* dst = pws + (size_t)c * ROWS + b * M;
#pragma unroll
    for (int k = 0; k < KPT; ++k) {
        float d2 = fmaxf(fmaf(-2.0f, mq[k], k2[k]), 0.0f);
        dst[t + k * TPB] = d2;
    }
}

// K2: column-min over the NSPLIT partials, sqrt, per-block partial sums.
// 32 blocks x 128 threads = 4096 threads, one (b,m) row each.
__global__ __launch_bounds__(128) void p2p_colmin(
        const float* __restrict__ pws, float* __restrict__ bsum) {
    __shared__ float sbuf[2];
    const int row = blockIdx.x * 128 + threadIdx.x;
    float v = INFINITY;
    // Per c-step the 128 threads read 128 consecutive floats (coalesced).
#pragma unroll 4
    for (int c = 0; c < NSPLIT; ++c)
        v = fminf(v, pws[(size_t)c * ROWS + row]);
    float s = sqrtf(v);
    // wave64 shuffle reduce, 2 waves per block
#pragma unroll
    for (int off = 32; off > 0; off >>= 1) s += __shfl_down(s, off, 64);
    const int t = threadIdx.x;
    if ((t & 63) == 0) sbuf[t >> 6] = s;
    __syncthreads();
    if (t == 0) bsum[blockIdx.x] = sbuf[0] + sbuf[1];
}

// K3: sum the 32 block sums, divide, write the scalar. Deterministic.
__global__ __launch_bounds__(64) void p2p_final(
        const float* __restrict__ bsum, float* __restrict__ out) {
    const int t = threadIdx.x;
    float s = (t < 32) ? bsum[t] : 0.f;
#pragma unroll
    for (int off = 32; off > 0; off >>= 1) s += __shfl_down(s, off, 64);
    if (t == 0) out[0] = s / (float)ROWS;
}

extern "C" void kernel_launch(void* const* d_in, const int* in_sizes, int n_in,
                              void* d_out, int out_size, void* d_ws, size_t ws_size,
                              hipStream_t stream) {
    const float* kp = (const float*)d_in[0];   // [B,3,M]
    const float* pc = (const float*)d_in[1];   // [B,3,N]
    float* out = (float*)d_out;
    float* pws = (float*)d_ws;                 // 4 MiB partials + 32 sums

    p2p_partial<<<BATCH * NSPLIT, TPB, 0, stream>>>(kp, pc, pws);
    p2p_colmin<<<32, 128, 0, stream>>>(pws, pws + BSUM_OFF);
    p2p_final<<<1, 64, 0, stream>>>(pws + BSUM_OFF, out);
}

// Round 5
// 81.936 us; speedup vs baseline: 1.3284x; 1.3284x over previous
//
#include <hip/hip_runtime.h>
#include <math.h>

// keypoints [B,3,M] f32, pc [B,3,N] f32.
#define BATCH 4
#define M 1024
#define N 32768
#define NSPLIT 256                 // pc chunks per batch
#define CHUNK (N / NSPLIT)         // 128 points staged in LDS per block
#define TPB 512
#define KPT 2                      // 512 thr * 2 = 1024 = M
#define ROWS (BATCH * M)           // 4096

// K2 geometry: 64 blocks x 256 threads; each block owns 64 rows.
#define K2_BLOCKS 64
#define K2_TPB 256
#define K2_ROWS (ROWS / K2_BLOCKS) // 64

// ws layout (all plain float, no atomics):
//   pws[NSPLIT][ROWS]   partial min-d2 per chunk  = 4 MiB
//   bsum[K2_BLOCKS]     per-block sums from K2
#define BSUM_OFF (NSPLIT * ROWS)

__global__ __launch_bounds__(TPB) void p2p_partial(
        const float* __restrict__ kp, const float* __restrict__ pc,
        float* __restrict__ pws) {
    __shared__ __align__(16) float px[CHUNK];
    __shared__ __align__(16) float py[CHUNK];
    __shared__ __align__(16) float pz[CHUNK];
    __shared__ __align__(16) float pw[CHUNK];    // -0.5 * ||p||^2

    const int b = blockIdx.x / NSPLIT;
    const int c = blockIdx.x % NSPLIT;
    const int t = threadIdx.x;

    // Stage one pc chunk into LDS (coalesced), precompute -||p||^2/2.
    const float* pcb = pc + (size_t)b * 3 * N + c * CHUNK;
    if (t < CHUNK) {
        float x = pcb[t], y = pcb[N + t], z = pcb[2 * N + t];
        px[t] = x; py[t] = y; pz[t] = z;
        pw[t] = -0.5f * fmaf(x, x, fmaf(y, y, z * z));
    }

    // Each thread owns KPT keypoints in registers (coalesced loads).
    const float* kpb = kp + (size_t)b * 3 * M;
    float kx[KPT], ky[KPT], kz[KPT], k2[KPT], mq[KPT];
#pragma unroll
    for (int k = 0; k < KPT; ++k) {
        int m = t + k * TPB;
        kx[k] = kpb[m];
        ky[k] = kpb[M + m];
        kz[k] = kpb[2 * M + m];
        k2[k] = fmaf(kx[k], kx[k], fmaf(ky[k], ky[k], kz[k] * kz[k]));
        mq[k] = -INFINITY;
    }
    __syncthreads();

    // Hot loop: min_p ||k-p||^2 = k2 - 2*max_p(k.p - ||p||^2/2).
    // Per pair: 3 fma + shared max3. Broadcast ds_read_b128 (uniform addr)
    // is cheap -> VALU-bound; 8 waves/SIMD hides LDS latency.
#pragma unroll 2
    for (int j = 0; j < CHUNK; j += 4) {
        float4 vx = *(const float4*)&px[j];
        float4 vy = *(const float4*)&py[j];
        float4 vz = *(const float4*)&pz[j];
        float4 vw = *(const float4*)&pw[j];
        float X[4] = {vx.x, vx.y, vx.z, vx.w};
        float Y[4] = {vy.x, vy.y, vy.z, vy.w};
        float Z[4] = {vz.x, vz.y, vz.z, vz.w};
        float W[4] = {vw.x, vw.y, vw.z, vw.w};
#pragma unroll
        for (int k = 0; k < KPT; ++k) {
            float q0 = fmaf(kz[k], Z[0], fmaf(ky[k], Y[0], fmaf(kx[k], X[0], W[0])));
            float q1 = fmaf(kz[k], Z[1], fmaf(ky[k], Y[1], fmaf(kx[k], X[1], W[1])));
            float q2 = fmaf(kz[k], Z[2], fmaf(ky[k], Y[2], fmaf(kx[k], X[2], W[2])));
            float q3 = fmaf(kz[k], Z[3], fmaf(ky[k], Y[3], fmaf(kx[k], X[3], W[3])));
            // fmaxf chains fuse to v_max3_f32 on gfx950
            mq[k] = fmaxf(fmaxf(mq[k], q0), q1);
            mq[k] = fmaxf(fmaxf(mq[k], q2), q3);
        }
    }

    // Epilogue: d2 = k2 - 2*qmax, clamp >= 0. Plain coalesced streaming store.
    float* dst = pws + (size_t)c * ROWS + b * M;
#pragma unroll
    for (int k = 0; k < KPT; ++k) {
        float d2 = fmaxf(fmaf(-2.0f, mq[k], k2[k]), 0.0f);
        dst[t + k * TPB] = d2;
    }
}

// K2: column-min over NSPLIT partials, coalesced + parallel.
// 64 blocks x 256 threads; block owns 64 rows; wave g covers c = g*64..g*64+63.
// Each wave-load reads 64 consecutive rows (256 B, fully coalesced); each
// thread's 64 loads have independent addresses -> pipelined, no latency chain.
__global__ __launch_bounds__(K2_TPB) void p2p_colmin(
        const float* __restrict__ pws, float* __restrict__ bsum) {
    __shared__ float smin[4][K2_ROWS];
    const int t = threadIdx.x;
    const int r = t & 63;
    const int g = t >> 6;                       // wave id, 0..3
    const int row = blockIdx.x * K2_ROWS + r;

    float v = INFINITY;
#pragma unroll 8
    for (int ci = 0; ci < NSPLIT / 4; ++ci) {
        int c = g * (NSPLIT / 4) + ci;
        v = fminf(v, pws[(size_t)c * ROWS + row]);
    }
    smin[g][r] = v;
    __syncthreads();

    if (t < 64) {
        float m = fminf(fminf(smin[0][t], smin[1][t]),
                        fminf(smin[2][t], smin[3][t]));
        float s = sqrtf(m);
#pragma unroll
        for (int off = 32; off > 0; off >>= 1) s += __shfl_down(s, off, 64);
        if (t == 0) bsum[blockIdx.x] = s;
    }
}

// K3: sum the 64 block sums, divide, write the scalar. Deterministic.
__global__ __launch_bounds__(64) void p2p_final(
        const float* __restrict__ bsum, float* __restrict__ out) {
    const int t = threadIdx.x;
    float s = bsum[t];
#pragma unroll
    for (int off = 32; off > 0; off >>= 1) s += __shfl_down(s, off, 64);
    if (t == 0) out[0] = s / (float)ROWS;
}

extern "C" void kernel_launch(void* const* d_in, const int* in_sizes, int n_in,
                              void* d_out, int out_size, void* d_ws, size_t ws_size,
                              hipStream_t stream) {
    const float* kp = (const float*)d_in[0];   // [B,3,M]
    const float* pc = (const float*)d_in[1];   // [B,3,N]
    float* out = (float*)d_out;
    float* pws = (float*)d_ws;                 // 4 MiB partials + 64 sums

    p2p_partial<<<BATCH * NSPLIT, TPB, 0, stream>>>(kp, pc, pws);
    p2p_colmin<<<K2_BLOCKS, K2_TPB, 0, stream>>>(pws, pws + BSUM_OFF);
    p2p_final<<<1, 64, 0, stream>>>(pws + BSUM_OFF, out);
}

// Round 7
// 81.254 us; speedup vs baseline: 1.3396x; 1.0084x over previous
//
#include <hip/hip_runtime.h>
#include <math.h>

// keypoints [B,3,M] f32, pc [B,3,N] f32.
#define BATCH 4
#define M 1024
#define N 32768
#define NSPLIT 256                 // pc chunks per batch
#define CHUNK (N / NSPLIT)         // 128 points staged in LDS per block
#define TPB 256
#define KPT 4                      // 256 thr * 4 = 1024 = M
#define ROWS (BATCH * M)           // 4096

// K2 geometry: 64 blocks x 256 threads; each block owns 64 rows.
#define K2_BLOCKS 64
#define K2_TPB 256
#define K2_ROWS (ROWS / K2_BLOCKS) // 64

// ws layout (all plain float, no atomics):
//   pws[NSPLIT][ROWS]   partial min-d2 per chunk  = 4 MiB
//   bsum[K2_BLOCKS]     per-block sums from K2
#define BSUM_OFF (NSPLIT * ROWS)

// Balance note (round-5 post-mortem): broadcast ds_read_b128 cost scales with
// waves*CHUNK. KPT=4/TPB=256 -> 16 waves/CU * 128 reads * ~8cy = 6.8us LDS
// ~= 6us VALU floor (3 fma + 0.5 max3 per pair). KPT=2/TPB=512 was 2x LDS-bound.
__global__ __launch_bounds__(TPB) void p2p_partial(
        const float* __restrict__ kp, const float* __restrict__ pc,
        float* __restrict__ pws) {
    __shared__ __align__(16) float px[CHUNK];
    __shared__ __align__(16) float py[CHUNK];
    __shared__ __align__(16) float pz[CHUNK];
    __shared__ __align__(16) float pw[CHUNK];    // -0.5 * ||p||^2

    const int b = blockIdx.x / NSPLIT;
    const int c = blockIdx.x % NSPLIT;
    const int t = threadIdx.x;

    // Stage one pc chunk into LDS (coalesced), precompute -||p||^2/2.
    const float* pcb = pc + (size_t)b * 3 * N + c * CHUNK;
    if (t < CHUNK) {
        float x = pcb[t], y = pcb[N + t], z = pcb[2 * N + t];
        px[t] = x; py[t] = y; pz[t] = z;
        pw[t] = -0.5f * fmaf(x, x, fmaf(y, y, z * z));
    }

    // Each thread owns KPT keypoints in registers (coalesced loads).
    const float* kpb = kp + (size_t)b * 3 * M;
    float kx[KPT], ky[KPT], kz[KPT], k2[KPT], mq[KPT];
#pragma unroll
    for (int k = 0; k < KPT; ++k) {
        int m = t + k * TPB;
        kx[k] = kpb[m];
        ky[k] = kpb[M + m];
        kz[k] = kpb[2 * M + m];
        k2[k] = fmaf(kx[k], kx[k], fmaf(ky[k], ky[k], kz[k] * kz[k]));
        mq[k] = -INFINITY;
    }
    __syncthreads();

    // Hot loop: min_p ||k-p||^2 = k2 - 2*max_p(k.p - ||p||^2/2).
    // Per pair: 3 fma + shared max3. 4 ds_read_b128 + ~52 VALU per iter.
#pragma unroll 2
    for (int j = 0; j < CHUNK; j += 4) {
        float4 vx = *(const float4*)&px[j];
        float4 vy = *(const float4*)&py[j];
        float4 vz = *(const float4*)&pz[j];
        float4 vw = *(const float4*)&pw[j];
        float X[4] = {vx.x, vx.y, vx.z, vx.w};
        float Y[4] = {vy.x, vy.y, vy.z, vy.w};
        float Z[4] = {vz.x, vz.y, vz.z, vz.w};
        float W[4] = {vw.x, vw.y, vw.z, vw.w};
#pragma unroll
        for (int k = 0; k < KPT; ++k) {
            float q0 = fmaf(kz[k], Z[0], fmaf(ky[k], Y[0], fmaf(kx[k], X[0], W[0])));
            float q1 = fmaf(kz[k], Z[1], fmaf(ky[k], Y[1], fmaf(kx[k], X[1], W[1])));
            float q2 = fmaf(kz[k], Z[2], fmaf(ky[k], Y[2], fmaf(kx[k], X[2], W[2])));
            float q3 = fmaf(kz[k], Z[3], fmaf(ky[k], Y[3], fmaf(kx[k], X[3], W[3])));
            // fmaxf chains fuse to v_max3_f32 on gfx950
            mq[k] = fmaxf(fmaxf(mq[k], q0), q1);
            mq[k] = fmaxf(fmaxf(mq[k], q2), q3);
        }
    }

    // Epilogue: d2 = k2 - 2*qmax, clamp >= 0. Plain coalesced streaming store.
    float* dst = pws + (size_t)c * ROWS + b * M;
#pragma unroll
    for (int k = 0; k < KPT; ++k) {
        float d2 = fmaxf(fmaf(-2.0f, mq[k], k2[k]), 0.0f);
        dst[t + k * TPB] = d2;
    }
}

// K2: column-min over NSPLIT partials, coalesced + parallel.
// 64 blocks x 256 threads; block owns 64 rows; wave g covers its c-range.
// Each wave-load reads 64 consecutive rows (256 B, fully coalesced); each
// thread's 64 loads have independent addresses -> pipelined, no latency chain.
__global__ __launch_bounds__(K2_TPB) void p2p_colmin(
        const float* __restrict__ pws, float* __restrict__ bsum) {
    __shared__ float smin[4][K2_ROWS];
    const int t = threadIdx.x;
    const int r = t & 63;
    const int g = t >> 6;                       // wave id, 0..3
    const int row = blockIdx.x * K2_ROWS + r;

    float v = INFINITY;
#pragma unroll 8
    for (int ci = 0; ci < NSPLIT / 4; ++ci) {
        int c = g * (NSPLIT / 4) + ci;
        v = fminf(v, pws[(size_t)c * ROWS + row]);
    }
    smin[g][r] = v;
    __syncthreads();

    if (t < 64) {
        float m = fminf(fminf(smin[0][t], smin[1][t]),
                        fminf(smin[2][t], smin[3][t]));
        float s = sqrtf(m);
#pragma unroll
        for (int off = 32; off > 0; off >>= 1) s += __shfl_down(s, off, 64);
        if (t == 0) bsum[blockIdx.x] = s;
    }
}

// K3: sum the 64 block sums, divide, write the scalar. Deterministic.
__global__ __launch_bounds__(64) void p2p_final(
        const float* __restrict__ bsum, float* __restrict__ out) {
    const int t = threadIdx.x;
    float s = bsum[t];
#pragma unroll
    for (int off = 32; off > 0; off >>= 1) s += __shfl_down(s, off, 64);
    if (t == 0) out[0] = s / (float)ROWS;
}

extern "C" void kernel_launch(void* const* d_in, const int* in_sizes, int n_in,
                              void* d_out, int out_size, void* d_ws, size_t ws_size,
                              hipStream_t stream) {
    const float* kp = (const float*)d_in[0];   // [B,3,M]
    const float* pc = (const float*)d_in[1];   // [B,3,N]
    float* out = (float*)d_out;
    float* pws = (float*)d_ws;                 // 4 MiB partials + 64 sums

    p2p_partial<<<BATCH * NSPLIT, TPB, 0, stream>>>(kp, pc, pws);
    p2p_colmin<<<K2_BLOCKS, K2_TPB, 0, stream>>>(pws, pws + BSUM_OFF);
    p2p_final<<<1, 64, 0, stream>>>(pws + BSUM_OFF, out);
}